// Round 1
// baseline (253.873 us; speedup 1.0000x reference)
//
#include <hip/hip_runtime.h>
#include <math.h>

// ---------------------------------------------------------------------------
// out[b][s] = <v_b| I_{2^s} (x) W (x) I |v_b> / <v_b|v_b>,  s=0..12
// R7: SINGLE-READ design. One 1024-thread block per 2 rows (256 blocks, 1/CU).
// Row streamed in 8x8KB fp32 chunks -> fp16 in LDS (128 KB = full row).
//  - chunk-local windows s=3..12 computed per chunk (pair_unit/unit9/10/11
//    reused verbatim from the verified R4/R6 kernel + new unitW0 for s=12),
//    overlapped with next-chunk global loads (issue-early / write-late).
//  - full-row windows: s=0 (bits 12..15) single 16x16 Gram; s=1,2 fused as a
//    32x32 Gram over bits 10..14 (pairF), computed at row end while the next
//    row's chunk-0 loads are in flight.
// HBM traffic = 128 MiB exactly (one fp32 read). No second pass, no XCD
// dispatch assumptions.
// ws layout (floats): [0..256) W row-major; [256..) acc[row*14+s], slot13=sumsq
// ---------------------------------------------------------------------------

typedef _Float16 f16x8 __attribute__((ext_vector_type(8)));
typedef float f32x4 __attribute__((ext_vector_type(4)));
typedef float f32x16 __attribute__((ext_vector_type(16)));
#define MFMAH(a, b, c) __builtin_amdgcn_mfma_f32_16x16x32_f16((a), (b), (c), 0, 0, 0)
#define MFMA32(a, b, c) __builtin_amdgcn_mfma_f32_32x32x16_f16((a), (b), (c), 0, 0, 0)

union Frag { _Float16 h[8]; f16x8 v; uint2 q[2]; unsigned int w[4]; };

__device__ __forceinline__ int swz(int g) { return g ^ (g >> 5); }

__device__ __forceinline__ float wave_sum(float x) {
    #pragma unroll
    for (int off = 32; off > 0; off >>= 1) x += __shfl_down(x, off, 64);
    return x;
}

// ------------------------- setup: build W on device -------------------------
using c2 = float2;
__device__ __forceinline__ c2 cmul(c2 a, c2 b) {
    return make_float2(a.x * b.x - a.y * b.y, a.x * b.y + a.y * b.x);
}
__device__ __forceinline__ c2 cadd(c2 a, c2 b) { return make_float2(a.x + b.x, a.y + b.y); }

__device__ __forceinline__ c2 kelem(const c2 u[4][2][2], int i, int j) {
    c2 p = cmul(u[0][(i >> 3) & 1][(j >> 3) & 1], u[1][(i >> 2) & 1][(j >> 2) & 1]);
    p = cmul(p, u[2][(i >> 1) & 1][(j >> 1) & 1]);
    p = cmul(p, u[3][i & 1][j & 1]);
    return p;
}
__device__ __forceinline__ int fperm(int x) {
    int b3 = (x >> 3) & 1, b2 = (x >> 2) & 1, b1 = (x >> 1) & 1, b0 = x & 1;
    b2 ^= b3; b1 ^= b2; b0 ^= b1; b3 ^= b0;
    return (b3 << 3) | (b2 << 2) | (b1 << 1) | b0;
}

__global__ __launch_bounds__(256) void setup_kernel(const float* __restrict__ weight,
                                                    float* __restrict__ ws) {
    __shared__ c2 ush[3][4][2][2];
    __shared__ c2 A[256], B[256];
    const int t = threadIdx.x;

    if (t < 12) {
        const int r = t / 4, q = t % 4;
        const float a = weight[12 * r + 3 * q + 0];
        const float b = weight[12 * r + 3 * q + 1];
        const float c = weight[12 * r + 3 * q + 2];
        const float ca = cosf(0.5f * a), sa = sinf(0.5f * a);
        const float cc = cosf(0.5f * c), sc = sinf(0.5f * c);
        const c2 e = make_float2(cosf(0.5f * b), -sinf(0.5f * b));
        const c2 eb = make_float2(e.x, -e.y);
        ush[r][q][0][0] = make_float2(cc * ca * e.x - sc * sa * eb.x, cc * ca * e.y - sc * sa * eb.y);
        ush[r][q][0][1] = make_float2(-cc * sa * e.x - sc * ca * eb.x, -cc * sa * e.y - sc * ca * eb.y);
        ush[r][q][1][0] = make_float2(sc * ca * e.x + cc * sa * eb.x, sc * ca * e.y + cc * sa * eb.y);
        ush[r][q][1][1] = make_float2(-sc * sa * e.x + cc * ca * eb.x, -sc * sa * e.y + cc * ca * eb.y);
    }
    __syncthreads();

    const int i = t >> 4, j = t & 15;
    A[t] = kelem(ush[0], i, j);
    __syncthreads();
    B[fperm(i) * 16 + j] = A[t];
    __syncthreads();
    {
        c2 acc = make_float2(0.f, 0.f);
        #pragma unroll
        for (int k = 0; k < 16; ++k) acc = cadd(acc, cmul(kelem(ush[1], i, k), B[k * 16 + j]));
        __syncthreads();
        A[t] = acc;
    }
    __syncthreads();
    B[fperm(i) * 16 + j] = A[t];
    __syncthreads();
    {
        c2 acc = make_float2(0.f, 0.f);
        #pragma unroll
        for (int k = 0; k < 16; ++k) acc = cadd(acc, cmul(kelem(ush[2], i, k), B[k * 16 + j]));
        __syncthreads();
        A[t] = acc;
    }
    __syncthreads();
    {
        float wr = 0.f;
        #pragma unroll
        for (int k = 0; k < 16; ++k) {
            const c2 a = A[k * 16 + i];
            const c2 b = A[(k ^ 15) * 16 + j];
            wr += a.x * b.x + a.y * b.y;
        }
        ws[t] = wr;
    }
    for (int z = t; z < 512 * 14; z += 256) ws[256 + z] = 0.f;
}

// ----------------------------- unit helpers ---------------------------------

__device__ __forceinline__ void contract16(const float* __restrict__ Wl, const f32x4& acc,
                                           int i, int h, int l, float* dst) {
    const float4 wr = *(const float4*)&Wl[(i << 4) + (h << 2)];
    float q = wr.x * acc[0] + wr.y * acc[1] + wr.z * acc[2] + wr.w * acc[3];
    q = wave_sum(q);
    if (l == 0) atomicAdd(dst, q);
}

// Epilogue of a fused 32x32 Gram over a 5-bit window-union.
// qa: window = union>>1 (sum over union's low bit); qb: window = union&15
// (sum over union's top bit). C/D: col = lane&31, row = (r&3)+8*(r>>2)+4*(l>>5).
__device__ __forceinline__ void pair_contract(const f32x16& acc, const float* __restrict__ Wl,
                                              int Jp, int h2, int l,
                                              float* dqa, float* dqb) {
    float qa = 0.f, qb = 0.f;
    #pragma unroll
    for (int r2 = 0; r2 < 8; ++r2) {
        const int r = 2 * r2;
        const int J = (r & 3) + 8 * (r >> 2) + 4 * h2;
        qa += Wl[((J >> 1) << 4) + (Jp >> 1)] * ((Jp & 1) ? acc[r + 1] : acc[r]);
    }
    #pragma unroll
    for (int r = 0; r < 8; ++r) {
        const int J = (r & 3) + 8 * (r >> 2) + 4 * h2;
        qb += Wl[((J & 15) << 4) + (Jp & 15)] * ((Jp & 16) ? acc[r + 8] : acc[r]);
    }
    qa = wave_sum(qa);
    qb = wave_sum(qb);
    if (l == 0) { atomicAdd(dqa, qa); atomicAdd(dqb, qb); }
}

// Paired starts (S, S+1), S in {3,5,7}: 32x32x16 Gram over the 5-bit union.
template <int S>
__device__ __forceinline__ void pair_unit(const unsigned short* __restrict__ sh,
                                          const float* __restrict__ Wl,
                                          int l, int c0, int c1, float* accrow) {
    const int Jp = l & 31, h2 = l >> 5;
    f32x16 acc = {0.f, 0.f, 0.f, 0.f, 0.f, 0.f, 0.f, 0.f,
                  0.f, 0.f, 0.f, 0.f, 0.f, 0.f, 0.f, 0.f};
    #pragma unroll
    for (int cc = c0; cc < c1; ++cc) {
        int e0;
        if (S == 3)      e0 = (Jp << 8) + (cc << 4) + (h2 << 3);
        else if (S == 5) e0 = ((cc >> 2) << 11) + (Jp << 6) + ((cc & 3) << 4) + (h2 << 3);
        else             e0 = (cc << 9) + (Jp << 4) + (h2 << 3);
        const f16x8 f = *(const f16x8*)&sh[swz(e0 >> 3) << 3];
        acc = MFMA32(f, f, acc);
    }
    pair_contract(acc, Wl, Jp, h2, l, &accrow[S], &accrow[S + 1]);
}

__device__ __forceinline__ void unit9(const unsigned short* __restrict__ sh,
                                      const float* __restrict__ Wl,
                                      int i, int h, int l, int c0, int c1, float* accrow) {
    f32x4 acc = {0.f, 0.f, 0.f, 0.f};
    #pragma unroll
    for (int cc = c0; cc < c1; ++cc) {
        const int e0 = ((4 * cc + h) << 7) + (i << 3);
        const f16x8 f = *(const f16x8*)&sh[swz(e0 >> 3) << 3];
        acc = MFMAH(f, f, acc);
    }
    contract16(Wl, acc, i, h, l, &accrow[9]);
}

__device__ __forceinline__ void unit10(const unsigned short* __restrict__ sh,
                                       const float* __restrict__ Wl,
                                       int i, int h, int l, int c0, int c1, float* accrow) {
    f32x4 acc = {0.f, 0.f, 0.f, 0.f};
    #pragma unroll
    for (int cc = c0; cc < c1; ++cc) {
        const int a0 = 8 * cc + 2 * h;
        const int ea = a0 * 64 + 4 * i;
        const int eb = ea + 64;
        Frag fr;
        fr.q[0] = *(const uint2*)&sh[(swz(ea >> 3) << 3) + (ea & 7)];
        fr.q[1] = *(const uint2*)&sh[(swz(eb >> 3) << 3) + (eb & 7)];
        acc = MFMAH(fr.v, fr.v, acc);
    }
    contract16(Wl, acc, i, h, l, &accrow[10]);
}

__device__ __forceinline__ void unit11(const unsigned short* __restrict__ sh,
                                       const float* __restrict__ Wl,
                                       int i, int h, int l, int c0, int c1, float* accrow) {
    f32x4 acc = {0.f, 0.f, 0.f, 0.f};
    #pragma unroll
    for (int cc = c0; cc < c1; ++cc) {
        Frag fr;
        #pragma unroll
        for (int p = 0; p < 4; ++p) {
            const int ap = 16 * cc + 4 * h + p;
            const int e = ap * 32 + 2 * i;
            fr.w[p] = *(const unsigned int*)&sh[(swz(e >> 3) << 3) + (e & 7)];
        }
        acc = MFMAH(fr.v, fr.v, acc);
    }
    contract16(Wl, acc, i, h, l, &accrow[11]);
}

// NEW: s=12, window = element bits 0..3 within a chunk. 8x ds_read_u16 gather
// per MFMA (16 MFMAs/chunk split into quarters across 4 waves -> cheap).
__device__ __forceinline__ void unitW0(const unsigned short* __restrict__ sh,
                                       const float* __restrict__ Wl,
                                       int i, int h, int l, int c0, int c1, float* accrow) {
    f32x4 acc = {0.f, 0.f, 0.f, 0.f};
    #pragma unroll
    for (int cc = c0; cc < c1; ++cc) {
        Frag fr;
        #pragma unroll
        for (int p = 0; p < 8; ++p) {
            const int e = i + ((cc * 32 + h * 8 + p) << 4);
            fr.h[p] = *(const _Float16*)&sh[(swz(e >> 3) << 3) + (e & 7)];
        }
        acc = MFMAH(fr.v, fr.v, acc);
    }
    contract16(Wl, acc, i, h, l, &accrow[12]);
}

// ------------------------------ fused main ----------------------------------
// 256 blocks x 1024 threads; block b owns rows 2b, 2b+1. Full row (fp16) lives
// in 128 KB dynamic LDS as 8 chunks of 8192 elems, each chunk stored with the
// same swz() granule mapping the chunk units expect.
__global__ __launch_bounds__(1024) void main_kernel(const float* __restrict__ v,
                                                    const float* __restrict__ ws,
                                                    float* __restrict__ accg) {
    extern __shared__ __align__(16) unsigned short sh16[];   // 65536 fp16 = 128 KB
    __shared__ float Wl[256];
    const int t = threadIdx.x;
    const int l = t & 63, wv = t >> 6;
    const int i = l & 15, h = l >> 4;
    const int J = l & 31, h2 = l >> 5;
    if (t < 256) Wl[t] = ws[t];

    const float4* __restrict__ base = (const float4*)(v + ((size_t)blockIdx.x << 17));
    float* accrow = accg + (size_t)(2 * blockIdx.x) * 14;

    // prefetch chunk 0 (row 0)
    float4 a0 = base[2 * t], a1 = base[2 * t + 1];
    float ss = 0.f;

    for (int k = 0; k < 16; ++k) {
        // issue next chunk's loads BEFORE consuming current (T14 issue-early)
        float4 b0, b1;
        const bool more = (k < 15);
        if (more) {
            b0 = base[(k + 1) * 2048 + 2 * t];
            b1 = base[(k + 1) * 2048 + 2 * t + 1];
        }

        // consume current chunk: sumsq + cvt + LDS write (granule t -> swz(t))
        ss = fmaf(a0.x, a0.x, ss); ss = fmaf(a0.y, a0.y, ss);
        ss = fmaf(a0.z, a0.z, ss); ss = fmaf(a0.w, a0.w, ss);
        ss = fmaf(a1.x, a1.x, ss); ss = fmaf(a1.y, a1.y, ss);
        ss = fmaf(a1.z, a1.z, ss); ss = fmaf(a1.w, a1.w, ss);
        Frag fr;
        fr.h[0] = (_Float16)a0.x; fr.h[1] = (_Float16)a0.y;
        fr.h[2] = (_Float16)a0.z; fr.h[3] = (_Float16)a0.w;
        fr.h[4] = (_Float16)a1.x; fr.h[5] = (_Float16)a1.y;
        fr.h[6] = (_Float16)a1.z; fr.h[7] = (_Float16)a1.w;
        const int c = k & 7;
        *(f16x8*)&sh16[(c << 13) + (swz(t) << 3)] = fr.v;
        __syncthreads();   // chunk c visible; next-chunk loads in flight

        // chunk-local windows s=3..12 (16 waves, 16 tasks)
        const unsigned short* sh = &sh16[c << 13];
        const int half = (wv & 1) << 3;
        if (wv < 2)       pair_unit<3>(sh, Wl, l, half, half + 8, accrow);
        else if (wv < 4)  pair_unit<5>(sh, Wl, l, half, half + 8, accrow);
        else if (wv < 6)  pair_unit<7>(sh, Wl, l, half, half + 8, accrow);
        else if (wv < 8)  unit9 (sh, Wl, i, h, l, half, half + 8, accrow);
        else if (wv < 10) unit10(sh, Wl, i, h, l, half, half + 8, accrow);
        else if (wv < 12) unit11(sh, Wl, i, h, l, half, half + 8, accrow);
        else {
            const int q0 = (wv - 12) << 2;
            unitW0(sh, Wl, i, h, l, q0, q0 + 4, accrow);
        }

        if (c == 7) {
            // ---- full-row units (next row's chunk-0 loads already in flight)
            // s=0: window = bits 12..15, b128-friendly (e = i<<12 + k)
            {
                f32x4 acc = {0.f, 0.f, 0.f, 0.f};
                #pragma unroll
                for (int j = 0; j < 8; ++j) {
                    const int cc = (wv << 3) + j;               // 0..127
                    const int e = (i << 12) + cc * 32 + h * 8;
                    const f16x8 f = *(const f16x8*)
                        &sh16[((e >> 13) << 13) + (swz((e & 8191) >> 3) << 3)];
                    acc = MFMAH(f, f, acc);
                }
                contract16(Wl, acc, i, h, l, &accrow[0]);
            }
            // s=1,2 fused: 32x32 Gram over union = bits 10..14; K = bits {0..9,15}
            {
                f32x16 acc = {0.f, 0.f, 0.f, 0.f, 0.f, 0.f, 0.f, 0.f,
                              0.f, 0.f, 0.f, 0.f, 0.f, 0.f, 0.f, 0.f};
                #pragma unroll
                for (int j = 0; j < 8; ++j) {
                    const int cc = (wv << 3) + j;               // 0..127
                    const int kg = cc * 16 + h2 * 8;            // 11-bit K index
                    const int e = (J << 10) + (kg & 1023) + ((kg >> 10) << 15);
                    const f16x8 f = *(const f16x8*)
                        &sh16[((e >> 13) << 13) + (swz((e & 8191) >> 3) << 3)];
                    acc = MFMA32(f, f, acc);
                }
                pair_contract(acc, Wl, J, h2, l, &accrow[1], &accrow[2]);
            }
            {
                const float s2 = wave_sum(ss);
                if (l == 0) atomicAdd(&accrow[13], s2);
                ss = 0.f;
            }
            __syncthreads();   // all reads of this row done before overwrite
            accrow += 14;
        }
        if (more) { a0 = b0; a1 = b1; }
    }
}

__global__ __launch_bounds__(256) void finalize_kernel(const float* __restrict__ acc,
                                                       float* __restrict__ out) {
    const int idx = blockIdx.x * 256 + threadIdx.x;
    if (idx < 512 * 13) {
        const int row = idx / 13, s = idx % 13;
        out[idx] = acc[row * 14 + s] / acc[row * 14 + 13];
    }
}

extern "C" void kernel_launch(void* const* d_in, const int* in_sizes, int n_in,
                              void* d_out, int out_size, void* d_ws, size_t ws_size,
                              hipStream_t stream) {
    const float* vb = (const float*)d_in[0];
    const float* wt = (const float*)d_in[1];
    float* out = (float*)d_out;
    float* ws = (float*)d_ws;
    float* acc = ws + 256;

    static bool attr_set = false;
    if (!attr_set) {
        (void)hipFuncSetAttribute((const void*)main_kernel,
                                  hipFuncAttributeMaxDynamicSharedMemorySize, 131072);
        attr_set = true;
    }

    setup_kernel<<<1, 256, 0, stream>>>(wt, ws);
    main_kernel<<<256, 1024, 131072, stream>>>(vb, ws, acc);
    finalize_kernel<<<26, 256, 0, stream>>>(acc, out);
}